// Round 17
// baseline (164.947 us; speedup 1.0000x reference)
//
#include <hip/hip_runtime.h>
#include <math.h>
#include <stdint.h>

#define B 8
#define C 64
#define H 256
#define W 256
#define PSZ (H * W)          // 65536

// workspace layout
#define OFF_WC    256                        // 2*64*9 f64 = 9216 B
#define OFF_BIAS  9728                       // 2 f64

// ---------------------------------------------------------------------------
// prep: fold pointwise weight into depthwise taps (f64), fold biases.
// ---------------------------------------------------------------------------
__global__ void prep_kernel(const float* __restrict__ dw_w0, const float* __restrict__ dw_b0,
                            const float* __restrict__ pw_w0, const float* __restrict__ pw_b0,
                            const float* __restrict__ dw_w1, const float* __restrict__ dw_b1,
                            const float* __restrict__ pw_w1, const float* __restrict__ pw_b1,
                            double* __restrict__ wc, double* __restrict__ bias)
{
    int t = threadIdx.x;            // 0..127
    int which = t >> 6, c = t & 63;
    const float* dw = which ? dw_w1 : dw_w0;
    const float* pw = which ? pw_w1 : pw_w0;
    double p = (double)pw[c];
    #pragma unroll
    for (int k = 0; k < 9; ++k)
        wc[(which * 64 + c) * 9 + k] = p * (double)dw[c * 9 + k];
    if (c == 0) {
        const float* dwb = which ? dw_b1 : dw_b0;
        const float* pwb = which ? pw_b1 : pw_b0;
        double acc = (double)pwb[0];
        for (int cc = 0; cc < 64; ++cc) acc += (double)pw[cc] * (double)dwb[cc];
        bias[which] = acc;
    }
}

// ---------------------------------------------------------------------------
// one channel's compute for ONE output row from its 3 halo rows.
// Input row j uses weight row i=j (o = j-i = 0). JLO/JHI skip rows at edges.
// ---------------------------------------------------------------------------
template<int JLO, int JHI>
__device__ __forceinline__ void ch_compute(
    float4 r0, float4 r1, float4 r2,
    const double* __restrict__ wl9,   // 9 folded weights (uniform -> s_load)
    int lane, double acc[4])
{
    const float4 rr[3] = {r0, r1, r2};
    #pragma unroll
    for (int j = 0; j < 3; ++j) {
        if (j < JLO || j > JHI) continue;
        float lf = __shfl_up(rr[j].w, 1);
        float rf = __shfl_down(rr[j].x, 1);
        if (lane == 0)  lf = 0.0f;
        if (lane == 63) rf = 0.0f;
        double dd[6] = {(double)lf, (double)rr[j].x, (double)rr[j].y,
                        (double)rr[j].z, (double)rr[j].w, (double)rf};
        double wa = wl9[3 * j], wb = wl9[3 * j + 1], wcv = wl9[3 * j + 2];
        #pragma unroll
        for (int k = 0; k < 4; ++k)
            acc[k] += wa * dd[k] + wb * dd[k + 1] + wcv * dd[k + 2];
    }
}

// ---------------------------------------------------------------------------
// 32-channel accumulation, 2-channel unroll: 6 independent row loads issued
// straight-line, sched_barrier(0) pins them above the compute.
// Channel cc fully computed before cc+1 (sequential f64 order).
// ---------------------------------------------------------------------------
template<int JLO, int JHI>
__device__ __forceinline__ void accum_q(
    const float* __restrict__ xb,   // plane base + chunk*32*PSZ + lane*4
    const double* __restrict__ w9,  // folded weights for this chunk (uniform)
    const int gy[3], int lane, double acc[4])
{
    #pragma unroll 1
    for (int cc = 0; cc < 32; cc += 2) {
        const float* xcA = xb + (size_t)cc * PSZ;
        const float* xcB = xcA + PSZ;
        float4 a0 = *(const float4*)(xcA + gy[0]);
        float4 a1 = *(const float4*)(xcA + gy[1]);
        float4 a2 = *(const float4*)(xcA + gy[2]);
        float4 b0 = *(const float4*)(xcB + gy[0]);
        float4 b1 = *(const float4*)(xcB + gy[1]);
        float4 b2 = *(const float4*)(xcB + gy[2]);
        __builtin_amdgcn_sched_barrier(0);   // loads stay batched above compute
        ch_compute<JLO, JHI>(a0, a1, a2, w9 + cc * 9, lane, acc);
        ch_compute<JLO, JHI>(b0, b1, b2, w9 + (cc + 1) * 9, lane, acc);
    }
}

// ---------------------------------------------------------------------------
// FUSED kernel: score (both inputs) + sigmoid + select + count for ONE
// (batch, row). 256 threads = 4 waves = 2 inputs x 2 chunks of 32 channels.
// Occupancy-shaped: 2048 blocks = 8/CU; LDS ~8.5 KB; acc[4] keeps VGPR <= 64
// -> all three limits allow 32 waves/CU (the 41%-occupancy wall of rounds
// 15/16 was the 512-thread/33KB block shape).
// f64 end-to-end so the argmax selection matches the f64 numpy reference.
// ---------------------------------------------------------------------------
__global__ __launch_bounds__(256) void fused_kernel(
    const float* __restrict__ x0, const float* __restrict__ x1,
    const double* __restrict__ wc, const double* __restrict__ bias,
    float* __restrict__ out, unsigned int* __restrict__ count1)
{
    __shared__ double sred[2][2][4][64];   // 8 KiB [which][chunk][k][lane]; reused for f
    __shared__ unsigned int scnt;

    // XCD-bijective swizzle (2048 = 8*256): adjacent rows share an XCD.
    const int n    = blockIdx.x;
    const int task = (n & 7) * 256 + (n >> 3);
    const int b    = task >> 8;          // 0..7
    const int y    = task & 255;         // row

    const int tid   = threadIdx.x;
    const int w     = tid >> 6;          // wave 0..3
    const int lane  = tid & 63;
    const int which = w >> 1;            // input 0/1
    const int chunk = w & 1;             // channel half (32 ch)

    if (tid == 0) scnt = 0;

    const float* xin = which ? x1 : x0;
    const float* xb  = xin + (size_t)b * C * PSZ + (size_t)(chunk * 32) * PSZ + lane * 4;
    const double* w9 = wc + which * (C * 9) + (chunk * 32) * 9;

    int gy[3];
    #pragma unroll
    for (int j = 0; j < 3; ++j) {
        int r = y - 1 + j;
        r = r < 0 ? 0 : (r > H - 1 ? H - 1 : r);   // clamped; edge rows skipped
        gy[j] = r * W;
    }

    double acc[4] = {};   // 4 px of this row

    if (y == 0)            accum_q<1, 2>(xb, w9, gy, lane, acc);
    else if (y == H - 1)   accum_q<0, 1>(xb, w9, gy, lane, acc);
    else                   accum_q<0, 2>(xb, w9, gy, lane, acc);

    #pragma unroll
    for (int k = 0; k < 4; ++k)
        sred[which][chunk][k][lane] = acc[k];
    __syncthreads();

    // f for 512 (which,px) cells: 2 per thread, into registers first.
    double fv0, fv1;
    {
        int idx = tid;                       // 0..255 -> which 0
        int wh = idx >> 8, px = idx & 255;
        int k = px & 3, l = px >> 2;
        double s = sred[wh][0][k][l] + sred[wh][1][k][l] + bias[wh];
        fv0 = 1.0 + 1.0 / (1.0 + exp(-s));
    }
    {
        int idx = 256 + tid;                 // which 1
        int wh = idx >> 8, px = idx & 255;
        int k = px & 3, l = px >> 2;
        double s = sred[wh][0][k][l] + sred[wh][1][k][l] + bias[wh];
        fv1 = 1.0 + 1.0 / (1.0 + exp(-s));
    }
    __syncthreads();                         // all sred reads done

    double* sf = &sred[0][0][0][0];          // reuse as flat [which*256 + px]
    sf[tid] = fv0;
    sf[256 + tid] = fv1;
    __syncthreads();

    // ---- select phase: 1 row x 64 ch, x rows L2/L3-hot, write out ----
    const int tx = tid & 63;                 // float4 column
    const int tc = tid >> 6;                 // 0..3 channel group

    double g0[4], g1[4];
    #pragma unroll
    for (int j = 0; j < 4; ++j) {
        g0[j] = sf[tx * 4 + j];
        g1[j] = sf[256 + tx * 4 + j];
    }

    unsigned int cnt = 0;
    const size_t base = (size_t)b * C * PSZ + (size_t)y * W + (size_t)tx * 4;
    #pragma unroll 1
    for (int ci = tc; ci < C; ci += 4) {
        size_t off = base + (size_t)ci * PSZ;
        float4 a  = *(const float4*)(x0 + off);
        float4 bb = *(const float4*)(x1 + off);
        float4 r;
        { double v0=(double)a.x*g0[0], v1=(double)bb.x*g1[0]; bool s1=(v1>v0); cnt+=s1; r.x=s1?bb.x:a.x; }
        { double v0=(double)a.y*g0[1], v1=(double)bb.y*g1[1]; bool s1=(v1>v0); cnt+=s1; r.y=s1?bb.y:a.y; }
        { double v0=(double)a.z*g0[2], v1=(double)bb.z*g1[2]; bool s1=(v1>v0); cnt+=s1; r.z=s1?bb.z:a.z; }
        { double v0=(double)a.w*g0[3], v1=(double)bb.w*g1[3]; bool s1=(v1>v0); cnt+=s1; r.w=s1?bb.w:a.w; }
        *(float4*)(out + off) = r;
    }

    atomicAdd(&scnt, cnt);
    __syncthreads();
    if (tid == 0) atomicAdd(count1, scnt);
}

__global__ void finalize_kernel(const unsigned int* __restrict__ count1,
                                float* __restrict__ out_p)
{
    const double N = (double)B * C * H * W;
    double c1 = (double)(*count1);
    out_p[0] = (float)((N - c1) / N);
    out_p[1] = (float)(c1 / N);
}

extern "C" void kernel_launch(void* const* d_in, const int* in_sizes, int n_in,
                              void* d_out, int out_size, void* d_ws, size_t ws_size,
                              hipStream_t stream) {
    const float* x0    = (const float*)d_in[0];
    const float* x1    = (const float*)d_in[1];
    const float* dw_w0 = (const float*)d_in[2];
    const float* dw_b0 = (const float*)d_in[3];
    const float* pw_w0 = (const float*)d_in[4];
    const float* pw_b0 = (const float*)d_in[5];
    const float* dw_w1 = (const float*)d_in[6];
    const float* dw_b1 = (const float*)d_in[7];
    const float* pw_w1 = (const float*)d_in[8];
    const float* pw_b1 = (const float*)d_in[9];
    float* out = (float*)d_out;

    unsigned int* cnt  = (unsigned int*)d_ws;
    double*       wc   = (double*)((char*)d_ws + OFF_WC);
    double*       bias = (double*)((char*)d_ws + OFF_BIAS);

    (void)hipMemsetAsync(d_ws, 0, 256, stream);

    prep_kernel<<<1, 128, 0, stream>>>(dw_w0, dw_b0, pw_w0, pw_b0,
                                       dw_w1, dw_b1, pw_w1, pw_b1, wc, bias);

    fused_kernel<<<B * H, 256, 0, stream>>>(x0, x1, wc, bias, out, cnt);

    finalize_kernel<<<1, 1, 0, stream>>>(cnt, out + (size_t)B * C * H * W);
}

// Round 18
// 139.299 us; speedup vs baseline: 1.1841x; 1.1841x over previous
//
#include <hip/hip_runtime.h>
#include <math.h>
#include <stdint.h>

#define B 8
#define C 64
#define H 256
#define W 256
#define PSZ (H * W)          // 65536

// workspace layout
#define OFF_WC    256                        // 2*64*9 f64 = 9216 B
#define OFF_BIAS  9728                       // 2 f64

// ---------------------------------------------------------------------------
// prep: fold pointwise weight into depthwise taps (f64), fold biases.
// ---------------------------------------------------------------------------
__global__ void prep_kernel(const float* __restrict__ dw_w0, const float* __restrict__ dw_b0,
                            const float* __restrict__ pw_w0, const float* __restrict__ pw_b0,
                            const float* __restrict__ dw_w1, const float* __restrict__ dw_b1,
                            const float* __restrict__ pw_w1, const float* __restrict__ pw_b1,
                            double* __restrict__ wc, double* __restrict__ bias)
{
    int t = threadIdx.x;            // 0..127
    int which = t >> 6, c = t & 63;
    const float* dw = which ? dw_w1 : dw_w0;
    const float* pw = which ? pw_w1 : pw_w0;
    double p = (double)pw[c];
    #pragma unroll
    for (int k = 0; k < 9; ++k)
        wc[(which * 64 + c) * 9 + k] = p * (double)dw[c * 9 + k];
    if (c == 0) {
        const float* dwb = which ? dw_b1 : dw_b0;
        const float* pwb = which ? pw_b1 : pw_b0;
        double acc = (double)pwb[0];
        for (int cc = 0; cc < 64; ++cc) acc += (double)pw[cc] * (double)dwb[cc];
        bias[which] = acc;
    }
}

// ---------------------------------------------------------------------------
// one channel's compute: 6 halo rows -> 4 output rows (weight-row i ascending
// per output row, same FP order as all passing rounds).
// JLO/JHI skip invalid halo rows at image top/bottom (zero padding).
// ---------------------------------------------------------------------------
template<int JLO, int JHI>
__device__ __forceinline__ void ch_compute(
    const float4 rr[6],
    const double* __restrict__ wl9,   // 9 folded weights (uniform -> s_load)
    int lane, double acc[4][4])
{
    #pragma unroll
    for (int j = 0; j < 6; ++j) {
        if (j < JLO || j > JHI) continue;
        float lf = __shfl_up(rr[j].w, 1);
        float rf = __shfl_down(rr[j].x, 1);
        if (lane == 0)  lf = 0.0f;
        if (lane == 63) rf = 0.0f;
        double dd[6] = {(double)lf, (double)rr[j].x, (double)rr[j].y,
                        (double)rr[j].z, (double)rr[j].w, (double)rf};
        #pragma unroll
        for (int i = 0; i < 3; ++i) {
            const int o = j - i;                 // output row (0..3)
            if (o >= 0 && o < 4) {
                double wa = wl9[3 * i], wb = wl9[3 * i + 1], wcv = wl9[3 * i + 2];
                #pragma unroll
                for (int k = 0; k < 4; ++k)
                    acc[o][k] += wa * dd[k] + wb * dd[k + 1] + wcv * dd[k + 2];
            }
        }
    }
}

// ---------------------------------------------------------------------------
// 16-channel accumulation for a 4-row band; 6 row loads issued straight-line
// per channel, sched_barrier(0) pins them above the compute.
// ---------------------------------------------------------------------------
template<int JLO, int JHI>
__device__ __forceinline__ void accum_q(
    const float* __restrict__ xb,   // plane base + chunk*16*PSZ + lane*4
    const double* __restrict__ w9,  // folded weights for this chunk (uniform)
    const int gy[6], int lane, double acc[4][4])
{
    #pragma unroll 1
    for (int cc = 0; cc < 16; ++cc) {
        const float* xc = xb + (size_t)cc * PSZ;
        float4 rr[6];
        rr[0] = *(const float4*)(xc + gy[0]);
        rr[1] = *(const float4*)(xc + gy[1]);
        rr[2] = *(const float4*)(xc + gy[2]);
        rr[3] = *(const float4*)(xc + gy[3]);
        rr[4] = *(const float4*)(xc + gy[4]);
        rr[5] = *(const float4*)(xc + gy[5]);
        __builtin_amdgcn_sched_barrier(0);   // loads stay batched above compute
        ch_compute<JLO, JHI>(rr, w9 + cc * 9, lane, acc);
    }
}

// ---------------------------------------------------------------------------
// FUSED kernel: score (both inputs) + sigmoid + select + count for one
// (batch, 4-ROW band). 512 threads = 8 waves = 2 inputs x 4 chunks x 16 ch.
// 4-row bands cut score L2 traffic 2.0x -> 1.5x halo (round-17 experiment:
// dur tracks L2-level bytes at ~8 TB/s marginal). Cross-chunk reduction is
// SEQUENTIAL in a 16 KB LDS buffer (chunk0 write, chunk1..3 add, barriers)
// -> exact chunk-ascending f64 order of rounds 15/16 -> bit-identical f.
// ---------------------------------------------------------------------------
__global__ __launch_bounds__(512) void fused_kernel(
    const float* __restrict__ x0, const float* __restrict__ x1,
    const double* __restrict__ wc, const double* __restrict__ bias,
    float* __restrict__ out, unsigned int* __restrict__ count1)
{
    __shared__ double sacc[2][4][4][64];   // 16 KiB [which][row][k][lane]
    __shared__ double sf[2][4][256];       // 16 KiB f values [which][row][px]
    __shared__ unsigned int scnt;

    // XCD-bijective swizzle (512 = 8*64): adjacent bands share an XCD.
    const int n    = blockIdx.x;
    const int task = (n & 7) * 64 + (n >> 3);
    const int b    = task >> 6;          // 0..7
    const int band = task & 63;          // 0..63
    const int y0   = band * 4;

    const int tid   = threadIdx.x;
    const int w     = tid >> 6;          // wave 0..7
    const int lane  = tid & 63;
    const int which = w >> 2;            // input 0/1
    const int chunk = w & 3;             // channel quarter (16 ch)

    if (tid == 0) scnt = 0;

    const float* xin = which ? x1 : x0;
    const float* xb  = xin + (size_t)b * C * PSZ + (size_t)(chunk * 16) * PSZ + lane * 4;
    const double* w9 = wc + which * (C * 9) + (chunk * 16) * 9;

    int gy[6];
    #pragma unroll
    for (int j = 0; j < 6; ++j) {
        int r = y0 - 1 + j;
        r = r < 0 ? 0 : (r > H - 1 ? H - 1 : r);   // clamped; edge rows skipped
        gy[j] = r * W;
    }

    double acc[4][4] = {};   // [out-row][px]

    if (band == 0)       accum_q<1, 5>(xb, w9, gy, lane, acc);
    else if (band == 63) accum_q<0, 4>(xb, w9, gy, lane, acc);
    else                 accum_q<0, 5>(xb, w9, gy, lane, acc);

    // sequential chunk accumulation: exact ((c0+c1)+c2)+c3 order per cell.
    if (chunk == 0) {
        #pragma unroll
        for (int o = 0; o < 4; ++o)
            #pragma unroll
            for (int k = 0; k < 4; ++k)
                sacc[which][o][k][lane] = acc[o][k];
    }
    __syncthreads();
    #pragma unroll 1
    for (int cph = 1; cph < 4; ++cph) {
        if (chunk == cph) {
            #pragma unroll
            for (int o = 0; o < 4; ++o)
                #pragma unroll
                for (int k = 0; k < 4; ++k)
                    sacc[which][o][k][lane] += acc[o][k];
        }
        __syncthreads();
    }

    // f-phase: 2048 cells (2 which x 4 rows x 256 px), 4 per thread.
    #pragma unroll
    for (int it = 0; it < 4; ++it) {
        int idx = tid + it * 512;
        int wh  = idx >> 10;
        int row = (idx >> 8) & 3;
        int px  = idx & 255;
        int k = px & 3, l = px >> 2;
        double s = sacc[wh][row][k][l] + bias[wh];
        sf[wh][row][px] = 1.0 + 1.0 / (1.0 + exp(-s));
    }
    __syncthreads();

    // ---- select phase: 4 rows x 64 ch, x rows L2-hot, write out ----
    const int tx = tid & 63;                 // float4 column
    const int tc = tid >> 6;                 // 0..7 channel group

    unsigned int cnt = 0;
    const size_t base = (size_t)b * C * PSZ + (size_t)y0 * W + (size_t)tx * 4;
    #pragma unroll 1
    for (int row = 0; row < 4; ++row) {
        double g0[4], g1[4];
        #pragma unroll
        for (int j = 0; j < 4; ++j) {
            g0[j] = sf[0][row][tx * 4 + j];
            g1[j] = sf[1][row][tx * 4 + j];
        }
        const size_t rbase = base + (size_t)row * W;
        #pragma unroll 1
        for (int ci = tc; ci < C; ci += 8) {
            size_t off = rbase + (size_t)ci * PSZ;
            float4 a  = *(const float4*)(x0 + off);
            float4 bb = *(const float4*)(x1 + off);
            float4 r;
            { double v0=(double)a.x*g0[0], v1=(double)bb.x*g1[0]; bool s1=(v1>v0); cnt+=s1; r.x=s1?bb.x:a.x; }
            { double v0=(double)a.y*g0[1], v1=(double)bb.y*g1[1]; bool s1=(v1>v0); cnt+=s1; r.y=s1?bb.y:a.y; }
            { double v0=(double)a.z*g0[2], v1=(double)bb.z*g1[2]; bool s1=(v1>v0); cnt+=s1; r.z=s1?bb.z:a.z; }
            { double v0=(double)a.w*g0[3], v1=(double)bb.w*g1[3]; bool s1=(v1>v0); cnt+=s1; r.w=s1?bb.w:a.w; }
            *(float4*)(out + off) = r;
        }
    }

    atomicAdd(&scnt, cnt);
    __syncthreads();
    if (tid == 0) atomicAdd(count1, scnt);
}

__global__ void finalize_kernel(const unsigned int* __restrict__ count1,
                                float* __restrict__ out_p)
{
    const double N = (double)B * C * H * W;
    double c1 = (double)(*count1);
    out_p[0] = (float)((N - c1) / N);
    out_p[1] = (float)(c1 / N);
}

extern "C" void kernel_launch(void* const* d_in, const int* in_sizes, int n_in,
                              void* d_out, int out_size, void* d_ws, size_t ws_size,
                              hipStream_t stream) {
    const float* x0    = (const float*)d_in[0];
    const float* x1    = (const float*)d_in[1];
    const float* dw_w0 = (const float*)d_in[2];
    const float* dw_b0 = (const float*)d_in[3];
    const float* pw_w0 = (const float*)d_in[4];
    const float* pw_b0 = (const float*)d_in[5];
    const float* dw_w1 = (const float*)d_in[6];
    const float* dw_b1 = (const float*)d_in[7];
    const float* pw_w1 = (const float*)d_in[8];
    const float* pw_b1 = (const float*)d_in[9];
    float* out = (float*)d_out;

    unsigned int* cnt  = (unsigned int*)d_ws;
    double*       wc   = (double*)((char*)d_ws + OFF_WC);
    double*       bias = (double*)((char*)d_ws + OFF_BIAS);

    (void)hipMemsetAsync(d_ws, 0, 256, stream);

    prep_kernel<<<1, 128, 0, stream>>>(dw_w0, dw_b0, pw_w0, pw_b0,
                                       dw_w1, dw_b1, pw_w1, pw_b1, wc, bias);

    fused_kernel<<<B * (H / 4), 512, 0, stream>>>(x0, x1, wc, bias, out, cnt);

    finalize_kernel<<<1, 1, 0, stream>>>(cnt, out + (size_t)B * C * H * W);
}

// Round 19
// 130.408 us; speedup vs baseline: 1.2649x; 1.0682x over previous
//
#include <hip/hip_runtime.h>
#include <math.h>
#include <stdint.h>

#define B 8
#define C 64
#define H 256
#define W 256
#define PSZ (H * W)          // 65536

// workspace layout
#define OFF_WC    256                        // 2*64*9 f64 = 9216 B
#define OFF_BIAS  9728                       // 2 f64

// ---------------------------------------------------------------------------
// prep: fold pointwise weight into depthwise taps (f64), fold biases.
// ---------------------------------------------------------------------------
__global__ void prep_kernel(const float* __restrict__ dw_w0, const float* __restrict__ dw_b0,
                            const float* __restrict__ pw_w0, const float* __restrict__ pw_b0,
                            const float* __restrict__ dw_w1, const float* __restrict__ dw_b1,
                            const float* __restrict__ pw_w1, const float* __restrict__ pw_b1,
                            double* __restrict__ wc, double* __restrict__ bias)
{
    int t = threadIdx.x;            // 0..127
    int which = t >> 6, c = t & 63;
    const float* dw = which ? dw_w1 : dw_w0;
    const float* pw = which ? pw_w1 : pw_w0;
    double p = (double)pw[c];
    #pragma unroll
    for (int k = 0; k < 9; ++k)
        wc[(which * 64 + c) * 9 + k] = p * (double)dw[c * 9 + k];
    if (c == 0) {
        const float* dwb = which ? dw_b1 : dw_b0;
        const float* pwb = which ? pw_b1 : pw_b0;
        double acc = (double)pwb[0];
        for (int cc = 0; cc < 64; ++cc) acc += (double)pw[cc] * (double)dwb[cc];
        bias[which] = acc;
    }
}

// ---------------------------------------------------------------------------
// one channel's compute from 4 halo rows (FP order identical to round 15).
// ---------------------------------------------------------------------------
template<int JLO, int JHI>
__device__ __forceinline__ void ch_compute(
    float4 r0, float4 r1, float4 r2, float4 r3,
    const double* __restrict__ wl9,   // 9 folded weights (uniform -> s_load)
    int lane, double acc[2][4])
{
    double wl[9];
    #pragma unroll
    for (int t = 0; t < 9; ++t) wl[t] = wl9[t];

    const float4 rr[4] = {r0, r1, r2, r3};
    #pragma unroll
    for (int j = 0; j < 4; ++j) {
        if (j < JLO || j > JHI) continue;
        float lf = __shfl_up(rr[j].w, 1);
        float rf = __shfl_down(rr[j].x, 1);
        if (lane == 0)  lf = 0.0f;
        if (lane == 63) rf = 0.0f;
        double dd[6] = {(double)lf, (double)rr[j].x, (double)rr[j].y,
                        (double)rr[j].z, (double)rr[j].w, (double)rf};
        #pragma unroll
        for (int i = 0; i < 3; ++i) {
            const int o = j - i;                 // output row (0..1)
            if (o >= 0 && o < 2) {
                double wa = wl[3 * i], wb = wl[3 * i + 1], wcv = wl[3 * i + 2];
                #pragma unroll
                for (int k = 0; k < 4; ++k)
                    acc[o][k] += wa * dd[k] + wb * dd[k + 1] + wcv * dd[k + 2];
            }
        }
    }
}

// ---------------------------------------------------------------------------
// 16-channel accumulation, 2-channel unroll: 8 independent row loads issued
// straight-line, then sched_barrier(0) pins them ABOVE the compute.
// Channel cc computed fully before cc+1 -> bit-identical f.
// ---------------------------------------------------------------------------
template<int JLO, int JHI>
__device__ __forceinline__ void accum_q(
    const float* __restrict__ xb,   // plane base + chunk*16*PSZ + lane*4
    const double* __restrict__ w9,  // folded weights for this chunk (uniform)
    const int gy[4], int lane, double acc[2][4])
{
    #pragma unroll 1
    for (int cc = 0; cc < 16; cc += 2) {
        const float* xcA = xb + (size_t)cc * PSZ;
        const float* xcB = xcA + PSZ;
        float4 a0 = *(const float4*)(xcA + gy[0]);
        float4 a1 = *(const float4*)(xcA + gy[1]);
        float4 a2 = *(const float4*)(xcA + gy[2]);
        float4 a3 = *(const float4*)(xcA + gy[3]);
        float4 b0 = *(const float4*)(xcB + gy[0]);
        float4 b1 = *(const float4*)(xcB + gy[1]);
        float4 b2 = *(const float4*)(xcB + gy[2]);
        float4 b3 = *(const float4*)(xcB + gy[3]);
        __builtin_amdgcn_sched_barrier(0);   // loads stay batched above
        ch_compute<JLO, JHI>(a0, a1, a2, a3, w9 + cc * 9, lane, acc);
        ch_compute<JLO, JHI>(b0, b1, b2, b3, w9 + (cc + 1) * 9, lane, acc);
    }
}

// ---------------------------------------------------------------------------
// FUSED kernel: score (both inputs) + sigmoid + select + count for one
// (batch, 2-row band). 512 threads = 8 waves = 2 inputs x 4 chunks x 16 ch.
// f64 end-to-end; summation order identical to rounds 14/15/16 -> absmax 0.
// (Round-16 configuration verbatim: measured best at 129.3 us total.
//  Both perturbations — 1-row bands r17, 4-row bands + seq-reduce r18 —
//  regressed; this shape is the codegen-stable local optimum.)
// ---------------------------------------------------------------------------
__global__ __launch_bounds__(512) void fused_kernel(
    const float* __restrict__ x0, const float* __restrict__ x1,
    const double* __restrict__ wc, const double* __restrict__ bias,
    float* __restrict__ out, unsigned int* __restrict__ count1)
{
    __shared__ double sred[2][4][2][4][64];   // 32 KiB [which][chunk][row][k][lane]; reused for f
    __shared__ unsigned int scnt;

    // XCD-bijective swizzle (1024 = 8*128): adjacent bands share an XCD.
    const int n    = blockIdx.x;
    const int task = (n & 7) * 128 + (n >> 3);
    const int b    = task >> 7;          // 0..7
    const int band = task & 127;         // 0..127
    const int y0   = band * 2;

    const int tid   = threadIdx.x;
    const int w     = tid >> 6;          // wave 0..7
    const int lane  = tid & 63;
    const int which = w >> 2;            // input 0/1
    const int chunk = w & 3;             // channel quarter

    if (tid == 0) scnt = 0;

    const float* xin = which ? x1 : x0;
    const float* xb  = xin + (size_t)b * C * PSZ + (size_t)(chunk * 16) * PSZ + lane * 4;
    const double* w9 = wc + which * (C * 9) + (chunk * 16) * 9;

    int gy[4];
    #pragma unroll
    for (int j = 0; j < 4; ++j) {
        int r = y0 - 1 + j;
        r = r < 0 ? 0 : (r > H - 1 ? H - 1 : r);   // clamped; edge rows skipped
        gy[j] = r * W;
    }

    double acc[2][4] = {};   // [out-row][px]

    if (band == 0)        accum_q<1, 3>(xb, w9, gy, lane, acc);
    else if (band == 127) accum_q<0, 2>(xb, w9, gy, lane, acc);
    else                  accum_q<0, 3>(xb, w9, gy, lane, acc);

    #pragma unroll
    for (int o = 0; o < 2; ++o)
        #pragma unroll
        for (int k = 0; k < 4; ++k)
            sred[which][chunk][o][k][lane] = acc[o][k];
    __syncthreads();

    // f for 1024 (which,row,px) cells: 2 per thread, into registers first.
    double fv0, fv1;
    {
        int idx = tid;                       // it = 0
        int wh = idx >> 9, row = (idx >> 8) & 1, px = idx & 255;
        int k = px & 3, l = px >> 2;
        double s = sred[wh][0][row][k][l] + sred[wh][1][row][k][l]
                 + sred[wh][2][row][k][l] + sred[wh][3][row][k][l] + bias[wh];
        fv0 = 1.0 + 1.0 / (1.0 + exp(-s));
    }
    {
        int idx = 512 + tid;                 // it = 1
        int wh = idx >> 9, row = (idx >> 8) & 1, px = idx & 255;
        int k = px & 3, l = px >> 2;
        double s = sred[wh][0][row][k][l] + sred[wh][1][row][k][l]
                 + sred[wh][2][row][k][l] + sred[wh][3][row][k][l] + bias[wh];
        fv1 = 1.0 + 1.0 / (1.0 + exp(-s));
    }
    __syncthreads();                         // all sred reads done

    double* sf = &sred[0][0][0][0][0];       // reuse as flat [which*512 + row*256 + px]
    sf[tid] = fv0;
    sf[512 + tid] = fv1;
    __syncthreads();

    // ---- select phase: 2 rows x 64 ch, reading L2-hot x, writing out ----
    const int tx = tid & 63;                 // float4 column
    const int tc = tid >> 6;                 // 0..7 channel group

    double g0[2][4], g1[2][4];               // [row][j]
    #pragma unroll
    for (int row = 0; row < 2; ++row)
        #pragma unroll
        for (int j = 0; j < 4; ++j) {
            g0[row][j] = sf[row * 256 + tx * 4 + j];
            g1[row][j] = sf[512 + row * 256 + tx * 4 + j];
        }

    unsigned int cnt = 0;
    const size_t base = (size_t)b * C * PSZ + (size_t)y0 * W + (size_t)tx * 4;
    #pragma unroll 1
    for (int ci = tc; ci < C; ci += 8) {
        #pragma unroll
        for (int row = 0; row < 2; ++row) {
            size_t off = base + (size_t)ci * PSZ + (size_t)row * W;
            float4 a  = *(const float4*)(x0 + off);
            float4 bb = *(const float4*)(x1 + off);
            float4 r;
            { double v0=(double)a.x*g0[row][0], v1=(double)bb.x*g1[row][0]; bool s1=(v1>v0); cnt+=s1; r.x=s1?bb.x:a.x; }
            { double v0=(double)a.y*g0[row][1], v1=(double)bb.y*g1[row][1]; bool s1=(v1>v0); cnt+=s1; r.y=s1?bb.y:a.y; }
            { double v0=(double)a.z*g0[row][2], v1=(double)bb.z*g1[row][2]; bool s1=(v1>v0); cnt+=s1; r.z=s1?bb.z:a.z; }
            { double v0=(double)a.w*g0[row][3], v1=(double)bb.w*g1[row][3]; bool s1=(v1>v0); cnt+=s1; r.w=s1?bb.w:a.w; }
            *(float4*)(out + off) = r;
        }
    }

    atomicAdd(&scnt, cnt);
    __syncthreads();
    if (tid == 0) atomicAdd(count1, scnt);
}

__global__ void finalize_kernel(const unsigned int* __restrict__ count1,
                                float* __restrict__ out_p)
{
    const double N = (double)B * C * H * W;
    double c1 = (double)(*count1);
    out_p[0] = (float)((N - c1) / N);
    out_p[1] = (float)(c1 / N);
}

extern "C" void kernel_launch(void* const* d_in, const int* in_sizes, int n_in,
                              void* d_out, int out_size, void* d_ws, size_t ws_size,
                              hipStream_t stream) {
    const float* x0    = (const float*)d_in[0];
    const float* x1    = (const float*)d_in[1];
    const float* dw_w0 = (const float*)d_in[2];
    const float* dw_b0 = (const float*)d_in[3];
    const float* pw_w0 = (const float*)d_in[4];
    const float* pw_b0 = (const float*)d_in[5];
    const float* dw_w1 = (const float*)d_in[6];
    const float* dw_b1 = (const float*)d_in[7];
    const float* pw_w1 = (const float*)d_in[8];
    const float* pw_b1 = (const float*)d_in[9];
    float* out = (float*)d_out;

    unsigned int* cnt  = (unsigned int*)d_ws;
    double*       wc   = (double*)((char*)d_ws + OFF_WC);
    double*       bias = (double*)((char*)d_ws + OFF_BIAS);

    (void)hipMemsetAsync(d_ws, 0, 256, stream);

    prep_kernel<<<1, 128, 0, stream>>>(dw_w0, dw_b0, pw_w0, pw_b0,
                                       dw_w1, dw_b1, pw_w1, pw_b1, wc, bias);

    fused_kernel<<<B * (H / 2), 512, 0, stream>>>(x0, x1, wc, bias, out, cnt);

    finalize_kernel<<<1, 1, 0, stream>>>(cnt, out + (size_t)B * C * H * W);
}

// Round 20
// 129.484 us; speedup vs baseline: 1.2739x; 1.0071x over previous
//
#include <hip/hip_runtime.h>
#include <math.h>
#include <stdint.h>

#define B 8
#define C 64
#define H 256
#define W 256
#define PSZ (H * W)          // 65536

// workspace layout
#define OFF_WC    256                        // 2*64*9 f64 = 9216 B
#define OFF_BIAS  9728                       // 2 f64

// ---------------------------------------------------------------------------
// prep: fold pointwise weight into depthwise taps (f64), fold biases.
// ---------------------------------------------------------------------------
__global__ void prep_kernel(const float* __restrict__ dw_w0, const float* __restrict__ dw_b0,
                            const float* __restrict__ pw_w0, const float* __restrict__ pw_b0,
                            const float* __restrict__ dw_w1, const float* __restrict__ dw_b1,
                            const float* __restrict__ pw_w1, const float* __restrict__ pw_b1,
                            double* __restrict__ wc, double* __restrict__ bias)
{
    int t = threadIdx.x;            // 0..127
    int which = t >> 6, c = t & 63;
    const float* dw = which ? dw_w1 : dw_w0;
    const float* pw = which ? pw_w1 : pw_w0;
    double p = (double)pw[c];
    #pragma unroll
    for (int k = 0; k < 9; ++k)
        wc[(which * 64 + c) * 9 + k] = p * (double)dw[c * 9 + k];
    if (c == 0) {
        const float* dwb = which ? dw_b1 : dw_b0;
        const float* pwb = which ? pw_b1 : pw_b0;
        double acc = (double)pwb[0];
        for (int cc = 0; cc < 64; ++cc) acc += (double)pw[cc] * (double)dwb[cc];
        bias[which] = acc;
    }
}

// ---------------------------------------------------------------------------
// one channel's compute from 4 halo rows (FP order identical to round 15).
// ---------------------------------------------------------------------------
template<int JLO, int JHI>
__device__ __forceinline__ void ch_compute(
    float4 r0, float4 r1, float4 r2, float4 r3,
    const double* __restrict__ wl9,   // 9 folded weights (uniform -> s_load)
    int lane, double acc[2][4])
{
    double wl[9];
    #pragma unroll
    for (int t = 0; t < 9; ++t) wl[t] = wl9[t];

    const float4 rr[4] = {r0, r1, r2, r3};
    #pragma unroll
    for (int j = 0; j < 4; ++j) {
        if (j < JLO || j > JHI) continue;
        float lf = __shfl_up(rr[j].w, 1);
        float rf = __shfl_down(rr[j].x, 1);
        if (lane == 0)  lf = 0.0f;
        if (lane == 63) rf = 0.0f;
        double dd[6] = {(double)lf, (double)rr[j].x, (double)rr[j].y,
                        (double)rr[j].z, (double)rr[j].w, (double)rf};
        #pragma unroll
        for (int i = 0; i < 3; ++i) {
            const int o = j - i;                 // output row (0..1)
            if (o >= 0 && o < 2) {
                double wa = wl[3 * i], wb = wl[3 * i + 1], wcv = wl[3 * i + 2];
                #pragma unroll
                for (int k = 0; k < 4; ++k)
                    acc[o][k] += wa * dd[k] + wb * dd[k + 1] + wcv * dd[k + 2];
            }
        }
    }
}

// ---------------------------------------------------------------------------
// 16-channel accumulation, 2-channel unroll: 8 independent row loads issued
// straight-line, then sched_barrier(0) pins them ABOVE the compute.
// Channel cc computed fully before cc+1 -> bit-identical f.
// With launch_bounds(512,1) the allocator may assign the 8 loads DISTINCT
// registers (round 16/19: VGPR=56 -> overlapping regs -> WAR-serialized).
// ---------------------------------------------------------------------------
template<int JLO, int JHI>
__device__ __forceinline__ void accum_q(
    const float* __restrict__ xb,   // plane base + chunk*16*PSZ + lane*4
    const double* __restrict__ w9,  // folded weights for this chunk (uniform)
    const int gy[4], int lane, double acc[2][4])
{
    #pragma unroll 1
    for (int cc = 0; cc < 16; cc += 2) {
        const float* xcA = xb + (size_t)cc * PSZ;
        const float* xcB = xcA + PSZ;
        float4 a0 = *(const float4*)(xcA + gy[0]);
        float4 a1 = *(const float4*)(xcA + gy[1]);
        float4 a2 = *(const float4*)(xcA + gy[2]);
        float4 a3 = *(const float4*)(xcA + gy[3]);
        float4 b0 = *(const float4*)(xcB + gy[0]);
        float4 b1 = *(const float4*)(xcB + gy[1]);
        float4 b2 = *(const float4*)(xcB + gy[2]);
        float4 b3 = *(const float4*)(xcB + gy[3]);
        __builtin_amdgcn_sched_barrier(0);   // loads stay batched above
        ch_compute<JLO, JHI>(a0, a1, a2, a3, w9 + cc * 9, lane, acc);
        ch_compute<JLO, JHI>(b0, b1, b2, b3, w9 + (cc + 1) * 9, lane, acc);
    }
}

// ---------------------------------------------------------------------------
// FUSED kernel: score (both inputs) + sigmoid + select + count for one
// (batch, 2-row band). 512 threads = 8 waves = 2 inputs x 4 chunks x 16 ch.
// f64 end-to-end; summation order identical to rounds 14-19 -> absmax 0.
// ONE-VARIABLE CHANGE vs round 19: launch_bounds(512) -> (512, 1).
// LDS (33 KB) still caps at 4 blocks/CU, so occupancy is unchanged; the
// hint only releases the register budget so the 8-load batch can live in
// distinct VGPRs (true 8-deep memory-level parallelism per wave).
// ---------------------------------------------------------------------------
__global__ __launch_bounds__(512, 1) void fused_kernel(
    const float* __restrict__ x0, const float* __restrict__ x1,
    const double* __restrict__ wc, const double* __restrict__ bias,
    float* __restrict__ out, unsigned int* __restrict__ count1)
{
    __shared__ double sred[2][4][2][4][64];   // 32 KiB [which][chunk][row][k][lane]; reused for f
    __shared__ unsigned int scnt;

    // XCD-bijective swizzle (1024 = 8*128): adjacent bands share an XCD.
    const int n    = blockIdx.x;
    const int task = (n & 7) * 128 + (n >> 3);
    const int b    = task >> 7;          // 0..7
    const int band = task & 127;         // 0..127
    const int y0   = band * 2;

    const int tid   = threadIdx.x;
    const int w     = tid >> 6;          // wave 0..7
    const int lane  = tid & 63;
    const int which = w >> 2;            // input 0/1
    const int chunk = w & 3;             // channel quarter

    if (tid == 0) scnt = 0;

    const float* xin = which ? x1 : x0;
    const float* xb  = xin + (size_t)b * C * PSZ + (size_t)(chunk * 16) * PSZ + lane * 4;
    const double* w9 = wc + which * (C * 9) + (chunk * 16) * 9;

    int gy[4];
    #pragma unroll
    for (int j = 0; j < 4; ++j) {
        int r = y0 - 1 + j;
        r = r < 0 ? 0 : (r > H - 1 ? H - 1 : r);   // clamped; edge rows skipped
        gy[j] = r * W;
    }

    double acc[2][4] = {};   // [out-row][px]

    if (band == 0)        accum_q<1, 3>(xb, w9, gy, lane, acc);
    else if (band == 127) accum_q<0, 2>(xb, w9, gy, lane, acc);
    else                  accum_q<0, 3>(xb, w9, gy, lane, acc);

    #pragma unroll
    for (int o = 0; o < 2; ++o)
        #pragma unroll
        for (int k = 0; k < 4; ++k)
            sred[which][chunk][o][k][lane] = acc[o][k];
    __syncthreads();

    // f for 1024 (which,row,px) cells: 2 per thread, into registers first.
    double fv0, fv1;
    {
        int idx = tid;                       // it = 0
        int wh = idx >> 9, row = (idx >> 8) & 1, px = idx & 255;
        int k = px & 3, l = px >> 2;
        double s = sred[wh][0][row][k][l] + sred[wh][1][row][k][l]
                 + sred[wh][2][row][k][l] + sred[wh][3][row][k][l] + bias[wh];
        fv0 = 1.0 + 1.0 / (1.0 + exp(-s));
    }
    {
        int idx = 512 + tid;                 // it = 1
        int wh = idx >> 9, row = (idx >> 8) & 1, px = idx & 255;
        int k = px & 3, l = px >> 2;
        double s = sred[wh][0][row][k][l] + sred[wh][1][row][k][l]
                 + sred[wh][2][row][k][l] + sred[wh][3][row][k][l] + bias[wh];
        fv1 = 1.0 + 1.0 / (1.0 + exp(-s));
    }
    __syncthreads();                         // all sred reads done

    double* sf = &sred[0][0][0][0][0];       // reuse as flat [which*512 + row*256 + px]
    sf[tid] = fv0;
    sf[512 + tid] = fv1;
    __syncthreads();

    // ---- select phase: 2 rows x 64 ch, reading L2-hot x, writing out ----
    const int tx = tid & 63;                 // float4 column
    const int tc = tid >> 6;                 // 0..7 channel group

    double g0[2][4], g1[2][4];               // [row][j]
    #pragma unroll
    for (int row = 0; row < 2; ++row)
        #pragma unroll
        for (int j = 0; j < 4; ++j) {
            g0[row][j] = sf[row * 256 + tx * 4 + j];
            g1[row][j] = sf[512 + row * 256 + tx * 4 + j];
        }

    unsigned int cnt = 0;
    const size_t base = (size_t)b * C * PSZ + (size_t)y0 * W + (size_t)tx * 4;
    #pragma unroll 1
    for (int ci = tc; ci < C; ci += 8) {
        #pragma unroll
        for (int row = 0; row < 2; ++row) {
            size_t off = base + (size_t)ci * PSZ + (size_t)row * W;
            float4 a  = *(const float4*)(x0 + off);
            float4 bb = *(const float4*)(x1 + off);
            float4 r;
            { double v0=(double)a.x*g0[row][0], v1=(double)bb.x*g1[row][0]; bool s1=(v1>v0); cnt+=s1; r.x=s1?bb.x:a.x; }
            { double v0=(double)a.y*g0[row][1], v1=(double)bb.y*g1[row][1]; bool s1=(v1>v0); cnt+=s1; r.y=s1?bb.y:a.y; }
            { double v0=(double)a.z*g0[row][2], v1=(double)bb.z*g1[row][2]; bool s1=(v1>v0); cnt+=s1; r.z=s1?bb.z:a.z; }
            { double v0=(double)a.w*g0[row][3], v1=(double)bb.w*g1[row][3]; bool s1=(v1>v0); cnt+=s1; r.w=s1?bb.w:a.w; }
            *(float4*)(out + off) = r;
        }
    }

    atomicAdd(&scnt, cnt);
    __syncthreads();
    if (tid == 0) atomicAdd(count1, scnt);
}

__global__ void finalize_kernel(const unsigned int* __restrict__ count1,
                                float* __restrict__ out_p)
{
    const double N = (double)B * C * H * W;
    double c1 = (double)(*count1);
    out_p[0] = (float)((N - c1) / N);
    out_p[1] = (float)(c1 / N);
}

extern "C" void kernel_launch(void* const* d_in, const int* in_sizes, int n_in,
                              void* d_out, int out_size, void* d_ws, size_t ws_size,
                              hipStream_t stream) {
    const float* x0    = (const float*)d_in[0];
    const float* x1    = (const float*)d_in[1];
    const float* dw_w0 = (const float*)d_in[2];
    const float* dw_b0 = (const float*)d_in[3];
    const float* pw_w0 = (const float*)d_in[4];
    const float* pw_b0 = (const float*)d_in[5];
    const float* dw_w1 = (const float*)d_in[6];
    const float* dw_b1 = (const float*)d_in[7];
    const float* pw_w1 = (const float*)d_in[8];
    const float* pw_b1 = (const float*)d_in[9];
    float* out = (float*)d_out;

    unsigned int* cnt  = (unsigned int*)d_ws;
    double*       wc   = (double*)((char*)d_ws + OFF_WC);
    double*       bias = (double*)((char*)d_ws + OFF_BIAS);

    (void)hipMemsetAsync(d_ws, 0, 256, stream);

    prep_kernel<<<1, 128, 0, stream>>>(dw_w0, dw_b0, pw_w0, pw_b0,
                                       dw_w1, dw_b1, pw_w1, pw_b1, wc, bias);

    fused_kernel<<<B * (H / 2), 512, 0, stream>>>(x0, x1, wc, bias, out, cnt);

    finalize_kernel<<<1, 1, 0, stream>>>(cnt, out + (size_t)B * C * H * W);
}